// Round 9
// baseline (282.026 us; speedup 1.0000x reference)
//
#include <hip/hip_runtime.h>
#include <hip/hip_fp16.h>

#define NN 50000
#define EE 800000
#define NB_E2 1563       // ceil(400000/256): 2 edges/thread grids
#define NWIN 8
#define WIN 6250         // node window (8 * 6250 = 50000)
#define EPB 1024         // edges per fill chunk (256 thr x 4)
#define NCHUNK 782       // ceil(800000/1024)
#define NFILL (NCHUNK * 8)  // 6256 fill blocks
#define NGX 196          // ceil(50000/256) gemm row-blocks

// ---------------- degree count + rank ----------------
__global__ void k_count(const int* __restrict__ ei, int* cnt, int* __restrict__ rank) {
    int t = blockIdx.x * 256 + threadIdx.x;
    if (t < EE / 2) {
        int2 cc = *(const int2*)(ei + EE + 2 * t);
        int r0 = atomicAdd(&cnt[cc.x], 1);
        int r1 = atomicAdd(&cnt[cc.y], 1);
        *(int2*)(rank + 2 * t) = make_int2(r0, r1);
    }
}

// ---------------- scan pass 1: per-block exclusive scan + dis ----------------
__global__ void k_scan1(const int* __restrict__ cnt, int* sloc, int* bsum,
                        float* dis, int n) {
    __shared__ int s[256];
    int tid = threadIdx.x;
    int i = blockIdx.x * 256 + tid;
    int v = (i < n) ? cnt[i] : 0;
    if (i < n) dis[i] = rsqrtf((float)v + 1.0f);  // +1 self loop
    s[tid] = v;
    __syncthreads();
    for (int off = 1; off < 256; off <<= 1) {
        int t2 = 0;
        if (tid >= off) t2 = s[tid - off];
        __syncthreads();
        if (tid >= off) s[tid] += t2;
        __syncthreads();
    }
    if (i < n) sloc[i] = s[tid] - v;
    if (tid == 255) bsum[blockIdx.x] = s[255];
}

// ---------------- scan pass 2+3: finalize starts + sd ----------------
__global__ void k_scan23(const int* __restrict__ sloc, const int* __restrict__ bsum,
                         const int* __restrict__ cnt, int2* sd, int* starts,
                         int n, int nb) {
    __shared__ int sb[256];
    int tid = threadIdx.x, b = blockIdx.x;
    int v = (tid < nb && tid < b) ? bsum[tid] : 0;
    sb[tid] = v;
    __syncthreads();
    for (int off = 128; off; off >>= 1) {
        if (tid < off) sb[tid] += sb[tid + off];
        __syncthreads();
    }
    int boff = sb[0];
    int i = b * 256 + tid;
    if (i < n) {
        int st = sloc[i] + boff;
        sd[i] = make_int2(st, cnt[i]);
        starts[i] = st;
    }
}

// ---------------- GEMM body (shared): LDS-staged x, thread-per-row ----------------
__device__ __forceinline__ void gemm_body(
    int bx, int grp, int tid, float* xt,
    const float* __restrict__ x, const float* __restrict__ Wb,
    const float* __restrict__ Wc, const float* __restrict__ bc,
    const float* __restrict__ dis,
    __half* __restrict__ bsh, float* __restrict__ wcomb, int n)
{
    int row0 = bx * 256;
    int row = row0 + tid;
    bool valid = row < n;

    const float* W = (grp < 2) ? (Wb + grp * 32) : Wc;
    const int ldw = (grp < 2) ? 64 : 32;

    float acc[32];
#pragma unroll
    for (int c = 0; c < 32; c++) acc[c] = 0.f;

    for (int s = 0; s < 4; s++) {
        int base_k = s * 32;
        float4 v[8];
#pragma unroll
        for (int i = 0; i < 8; i++) {
            int idx = i * 256 + tid;
            int r = idx >> 3;
            int k4 = idx & 7;
            int gr = row0 + r;
            v[i] = (gr < n) ? *(const float4*)(x + (size_t)gr * 128 + base_k + k4 * 4)
                            : make_float4(0.f, 0.f, 0.f, 0.f);
        }
        __syncthreads();
#pragma unroll
        for (int i = 0; i < 8; i++) {
            int idx = i * 256 + tid;
            int r = idx >> 3;
            int k4 = idx & 7;
            xt[(k4 * 4 + 0) * 257 + r] = v[i].x;
            xt[(k4 * 4 + 1) * 257 + r] = v[i].y;
            xt[(k4 * 4 + 2) * 257 + r] = v[i].z;
            xt[(k4 * 4 + 3) * 257 + r] = v[i].w;
        }
        __syncthreads();

        const float* Ws = W + base_k * ldw;
#pragma unroll 8
        for (int k = 0; k < 32; k++) {
            float xs = xt[k * 257 + tid];
            const float* wk = Ws + k * ldw;
#pragma unroll
            for (int c = 0; c < 32; c++) acc[c] = fmaf(xs, wk[c], acc[c]);
        }
    }

    if (!valid) return;
    if (grp < 2) {
        float d = dis[row];
        __half2 hh[16];
#pragma unroll
        for (int c = 0; c < 16; c++)
            hh[c] = __floats2half2_rn(acc[2 * c] * d, acc[2 * c + 1] * d);
        uint4* bo = (uint4*)(bsh + (size_t)row * 64 + grp * 32);
        const uint4* src = (const uint4*)hh;
#pragma unroll
        for (int c = 0; c < 4; c++) bo[c] = src[c];
    } else {
        float4* wo = (float4*)(wcomb + (size_t)row * 32);
#pragma unroll
        for (int c = 0; c < 8; c++)
            wo[c] = make_float4(acc[4*c] + bc[4*c], acc[4*c+1] + bc[4*c+1],
                                acc[4*c+2] + bc[4*c+2], acc[4*c+3] + bc[4*c+3]);
    }
}

// ---------------- fused: CSR fill (atomic-free, XCD-windowed) | conv1 gemm ----------------
__global__ __launch_bounds__(256) void k_fill_gemm(
    const int* __restrict__ ei, const int* __restrict__ rank,
    const int* __restrict__ starts, int* __restrict__ csr,
    const float* __restrict__ x, const float* __restrict__ Wb,
    const float* __restrict__ Wc, const float* __restrict__ bc,
    const float* __restrict__ dis,
    __half* __restrict__ bsh, float* __restrict__ wcomb, int n)
{
    __shared__ float xt[32 * 257];
    int b = blockIdx.x;
    if (b < NFILL) {
        int w = b & 7;
        int chunk = b >> 3;
        int base = chunk * EPB + threadIdx.x * 4;
        int lo = w * WIN, hi = lo + WIN;
        if (base + 3 < EE) {
            int4 rr = *(const int4*)(ei + base);
            int4 cc = *(const int4*)(ei + EE + base);
            int4 rk = *(const int4*)(rank + base);
            if (cc.x >= lo && cc.x < hi) csr[starts[cc.x] + rk.x] = rr.x;
            if (cc.y >= lo && cc.y < hi) csr[starts[cc.y] + rk.y] = rr.y;
            if (cc.z >= lo && cc.z < hi) csr[starts[cc.z] + rk.z] = rr.z;
            if (cc.w >= lo && cc.w < hi) csr[starts[cc.w] + rk.w] = rr.w;
        } else {
            for (int e = 0; e < 4; e++) {
                int t = base + e;
                if (t < EE) {
                    int c = ei[EE + t];
                    if (c >= lo && c < hi) csr[starts[c] + rank[t]] = ei[t];
                }
            }
        }
        return;
    }
    int bb = b - NFILL;
    int grp = bb / NGX;
    int bx = bb - grp * NGX;
    gemm_body(bx, grp, threadIdx.x, xt, x, Wb, Wc, bc, dis, bsh, wcomb, n);
}

// ---------------- standalone gemm (conv2) ----------------
__global__ __launch_bounds__(256) void k_gemm(
    const float* __restrict__ x, const float* __restrict__ Wb,
    const float* __restrict__ Wc, const float* __restrict__ bc,
    const float* __restrict__ dis,
    __half* __restrict__ bsh, float* __restrict__ wcomb, int n)
{
    __shared__ float xt[32 * 257];
    gemm_body(blockIdx.x, blockIdx.y, threadIdx.x, xt, x, Wb, Wc, bc, dis,
              bsh, wcomb, n);
}

__device__ __forceinline__ void h8_to_f8(uint4 v, float* f) {
    float2 a = __half22float2(*(const __half2*)&v.x);
    float2 b = __half22float2(*(const __half2*)&v.y);
    float2 c = __half22float2(*(const __half2*)&v.z);
    float2 d = __half22float2(*(const __half2*)&v.w);
    f[0] = a.x; f[1] = a.y; f[2] = b.x; f[3] = b.y;
    f[4] = c.x; f[5] = c.y; f[6] = d.x; f[7] = d.y;
}

// ---------------- fused aggregate v3: one coalesced index load + uint4 row gathers ----------------
// lane = 8 edge-slots (g=lane>>3) x 8 chunks (q=lane&7, 16B each -> full 128B row/slot)
template<int LAYER2>
__global__ __launch_bounds__(256) void k_agg(
    const int* __restrict__ csr, const int2* __restrict__ sd,
    const __half* __restrict__ bsh, const float* __restrict__ dis,
    const float* __restrict__ wcomb, const float* __restrict__ bias,
    float* __restrict__ h,
    const float* __restrict__ Wcls, const float* __restrict__ bcls,
    float* __restrict__ p, int n)
{
    int wid = (blockIdx.x * 256 + threadIdx.x) >> 6;
    int lane = threadIdx.x & 63;
    if (wid >= n) return;
    int2 s2 = sd[wid];
    int start = s2.x, deg = s2.y;
    int g = lane >> 3, q = lane & 7;
    const uint4* bsp4 = (const uint4*)bsh;  // row = 8 x uint4

    float acc[8];
#pragma unroll
    for (int j = 0; j < 8; j++) acc[j] = 0.f;

    int nw = (deg + 63) >> 6;  // 64-edge windows (nw==1 for deg<=64, the common case)
    for (int wdw = 0; wdw < nw; wdw++) {
        int wb = wdw << 6;
        int rem = min(deg - wb, 64);
        int idxv = (lane < rem) ? csr[start + wb + lane] : 0;  // ONE coalesced load
        int e0 = 0;
        for (; e0 + 16 <= rem; e0 += 16) {  // 2 full-row gathers in flight
            int r0 = __shfl(idxv, e0 + g, 64);
            int r1 = __shfl(idxv, e0 + 8 + g, 64);
            uint4 v0 = bsp4[(size_t)r0 * 8 + q];
            uint4 v1 = bsp4[(size_t)r1 * 8 + q];
            float f0[8], f1[8];
            h8_to_f8(v0, f0);
            h8_to_f8(v1, f1);
#pragma unroll
            for (int j = 0; j < 8; j++) acc[j] += f0[j] + f1[j];
        }
        for (; e0 < rem; e0 += 8) {  // masked tail (<16 left)
            int r = __shfl(idxv, e0 + g, 64);  // inactive lanes got idxv=0 -> row 0, masked
            float m = (e0 + g < rem) ? 1.f : 0.f;
            uint4 v = bsp4[(size_t)r * 8 + q];
            float f[8];
            h8_to_f8(v, f);
#pragma unroll
            for (int j = 0; j < 8; j++) acc[j] = fmaf(f[j], m, acc[j]);
        }
    }

    // reduce across 8 slots (xor 8,16,32) -> all lanes with same q hold the total
#pragma unroll
    for (int off = 8; off <= 32; off <<= 1)
#pragma unroll
        for (int j = 0; j < 8; j++) acc[j] += __shfl_xor(acc[j], off, 64);

    // self-loop term (uniform add post-reduce) + dis scale
    uint4 sv = bsp4[(size_t)wid * 8 + q];
    float sf[8];
    h8_to_f8(sv, sf);
    float d = dis[wid];
#pragma unroll
    for (int j = 0; j < 8; j++) acc[j] = (acc[j] + sf[j]) * d;

    // transpose -> per-lane scalar: feature f = lane (chunk lane>>3, elem lane&7)
    int srcq = lane >> 3;  // lanes 0..7 have q = 0..7
    float v0 = __shfl(acc[0], srcq, 64);
    float v1 = __shfl(acc[1], srcq, 64);
    float v2 = __shfl(acc[2], srcq, 64);
    float v3 = __shfl(acc[3], srcq, 64);
    float v4 = __shfl(acc[4], srcq, 64);
    float v5 = __shfl(acc[5], srcq, 64);
    float v6 = __shfl(acc[6], srcq, 64);
    float v7 = __shfl(acc[7], srcq, 64);
    int jj = lane & 7;
    float a = (jj == 0) ? v0 : (jj == 1) ? v1 : (jj == 2) ? v2 : (jj == 3) ? v3
            : (jj == 4) ? v4 : (jj == 5) ? v5 : (jj == 6) ? v6 : v7;

    // combine: ch=lane and ch=64+lane
    int fh = lane & 15;
    float a0 = __shfl(a, fh, 64);
    float a1 = __shfl(a, 16 + fh, 64);
    float a2 = __shfl(a, 32 + fh, 64);
    float a3 = __shfl(a, 48 + fh, 64);
    const float* wn = wcomb + (size_t)wid * 32;
    int hd = lane >> 4;
    float s1 = bias[lane];
    float s2v = bias[64 + lane];
    s1 = fmaf(wn[hd * 4 + 0], a0, s1);
    s1 = fmaf(wn[hd * 4 + 1], a1, s1);
    s1 = fmaf(wn[hd * 4 + 2], a2, s1);
    s1 = fmaf(wn[hd * 4 + 3], a3, s1);
    s2v = fmaf(wn[(4 + hd) * 4 + 0], a0, s2v);
    s2v = fmaf(wn[(4 + hd) * 4 + 1], a1, s2v);
    s2v = fmaf(wn[(4 + hd) * 4 + 2], a2, s2v);
    s2v = fmaf(wn[(4 + hd) * 4 + 3], a3, s2v);

    if (!LAYER2) {
        s1 = fmaxf(s1, 0.f);
        s2v = fmaxf(s2v, 0.f);
        h[(size_t)wid * 128 + lane] = s1;
        h[(size_t)wid * 128 + 64 + lane] = s2v;
    } else {
        float r0 = s1 * Wcls[lane * 2 + 0] + s2v * Wcls[(64 + lane) * 2 + 0];
        float r1 = s1 * Wcls[lane * 2 + 1] + s2v * Wcls[(64 + lane) * 2 + 1];
        float r2 = s1 * Wcls[(128 + lane) * 2 + 0] + s2v * Wcls[(192 + lane) * 2 + 0];
        float r3 = s1 * Wcls[(128 + lane) * 2 + 1] + s2v * Wcls[(192 + lane) * 2 + 1];
#pragma unroll
        for (int off = 32; off; off >>= 1) {
            r0 += __shfl_xor(r0, off, 64);
            r1 += __shfl_xor(r1, off, 64);
            r2 += __shfl_xor(r2, off, 64);
            r3 += __shfl_xor(r3, off, 64);
        }
        if (lane == 0) {
            p[wid * 4 + 0] = r0 + bcls[0];
            p[wid * 4 + 1] = r1 + bcls[1];
            p[wid * 4 + 2] = r2;
            p[wid * 4 + 3] = r3;
        }
    }
}

// ---------------- edge output: 2 edges/thread ----------------
__global__ void k_edge(const int* __restrict__ ei, const float* __restrict__ p,
                       float* __restrict__ out)
{
    int t = blockIdx.x * blockDim.x + threadIdx.x;
    if (t >= EE / 2) return;
    int2 rr = *(const int2*)(ei + 2 * t);
    int2 cc = *(const int2*)(ei + EE + 2 * t);
    float2 pt0 = *(const float2*)(p + rr.x * 4);
    float2 pt1 = *(const float2*)(p + rr.y * 4);
    float2 pb0 = *(const float2*)(p + cc.x * 4 + 2);
    float2 pb1 = *(const float2*)(p + cc.y * 4 + 2);
    float4 o;
    o.x = pt0.x + pb0.x;
    o.y = pt0.y + pb0.y;
    o.z = pt1.x + pb1.x;
    o.w = pt1.y + pb1.y;
    *(float4*)(out + (size_t)t * 4) = o;
}

extern "C" void kernel_launch(void* const* d_in, const int* in_sizes, int n_in,
                              void* d_out, int out_size, void* d_ws, size_t ws_size,
                              hipStream_t stream) {
    const float* x    = (const float*)d_in[0];
    const int*   ei   = (const int*)d_in[1];
    const float* Wb1  = (const float*)d_in[2];
    const float* Wc1  = (const float*)d_in[3];
    const float* bc1  = (const float*)d_in[4];
    const float* b1   = (const float*)d_in[5];
    const float* Wb2  = (const float*)d_in[6];
    const float* Wc2  = (const float*)d_in[7];
    const float* bc2  = (const float*)d_in[8];
    const float* b2   = (const float*)d_in[9];
    const float* Wcls = (const float*)d_in[10];
    const float* bcls = (const float*)d_in[11];
    float* out = (float*)d_out;

    char* ws = (char*)d_ws;
    size_t off = 0;
    auto alloc = [&](size_t bytes) {
        void* pp = ws + off;
        off += (bytes + 15) & ~(size_t)15;
        return pp;
    };

    float*  dis    = (float*)alloc(50048 * 4);
    __half* bsh    = (__half*)alloc((size_t)NN * 64 * 2);
    float*  wcomb  = (float*)alloc((size_t)NN * 32 * 4);
    float*  h      = (float*)alloc((size_t)NN * 128 * 4);
    float*  p      = (float*)alloc((size_t)NN * 4 * 4);
    int*    cnt    = (int*)alloc(50048 * 4);
    int*    sloc   = (int*)alloc(50048 * 4);
    int*    starts = (int*)alloc(50048 * 4);
    int*    bsum   = (int*)alloc(256 * 4);
    int2*   sd     = (int2*)alloc((size_t)50048 * 8);
    int*    csr    = (int*)alloc((size_t)EE * 4);
    int*    rank   = (int*)alloc((size_t)EE * 4);

    const int B = 256;
    int gN   = (NN + B - 1) / B;   // 196
    int gN64 = (NN * 64) / B;      // 12500
    dim3 gG(NGX, 3);

    // CSR build (shared by both layers)
    hipMemsetAsync(cnt, 0, NN * sizeof(int), stream);
    k_count<<<NB_E2, B, 0, stream>>>(ei, cnt, rank);
    k_scan1<<<gN, B, 0, stream>>>(cnt, sloc, bsum, dis, NN);
    k_scan23<<<gN, B, 0, stream>>>(sloc, bsum, cnt, sd, starts, NN, gN);

    // fused: CSR fill | conv1 gemm
    k_fill_gemm<<<NFILL + NGX * 3, B, 0, stream>>>(
        ei, rank, starts, csr, x, Wb1, Wc1, bc1, dis, bsh, wcomb, NN);
    k_agg<0><<<gN64, B, 0, stream>>>(csr, sd, bsh, dis, wcomb, b1, h,
                                     Wcls, bcls, p, NN);

    // conv2 (+ fused edge-cls projection)
    k_gemm<<<gG, B, 0, stream>>>(h, Wb2, Wc2, bc2, dis, bsh, wcomb, NN);
    k_agg<1><<<gN64, B, 0, stream>>>(csr, sd, bsh, dis, wcomb, b2, h,
                                     Wcls, bcls, p, NN);

    // edge output
    k_edge<<<NB_E2, B, 0, stream>>>(ei, p, out);
}